// Round 1
// baseline (57.589 us; speedup 1.0000x reference)
//
#include <hip/hip_runtime.h>
#include <hip/hip_bf16.h>

// Problem constants
#define BB 32
#define NN 10
#define IN_DIM 65536
#define OUT_DIM 64
#define HEADS 8
#define DD 8            // OUT_DIM / HEADS
#define ROWS (BB*NN)    // 320 "bn" rows
#define K4 (IN_DIM/4)   // 16384 float4 per row
#define SPLITS 8
#define RGROUP 4        // rows per block in gemv
#define NGROUPS (ROWS/RGROUP)  // 80

// ---------------------------------------------------------------------------
// Kernel 1: Wh[h][k] = sum_{d=0..7} W[h*8+d][k]   (W is 64 x 65536 row-major)
// ---------------------------------------------------------------------------
__global__ __launch_bounds__(256) void wreduce_kernel(const float* __restrict__ W,
                                                      float* __restrict__ Wh) {
    int idx = blockIdx.x * blockDim.x + threadIdx.x;   // 0 .. 8*16384-1
    int h  = idx >> 14;        // / 16384
    int k4 = idx & 16383;      // % 16384
    const float4* W4 = (const float4*)W;
    float4 s = make_float4(0.f, 0.f, 0.f, 0.f);
#pragma unroll
    for (int d = 0; d < DD; ++d) {
        float4 v = W4[(h * DD + d) * K4 + k4];
        s.x += v.x; s.y += v.y; s.z += v.z; s.w += v.w;
    }
    ((float4*)Wh)[h * K4 + k4] = s;
}

// ---------------------------------------------------------------------------
// Kernel 2: partial GEMV. s[bn][h] = x[bn][:] . Wh[h][:]
// grid = NGROUPS * SPLITS blocks, 256 threads.
// block -> (row group g, k-split). Thread register-blocks 4 rows x 8 heads.
// Writes partials[split][bn][h]  (SPLITS x 320 x 8 floats)
// ---------------------------------------------------------------------------
__global__ __launch_bounds__(256) void gemv_part_kernel(const float* __restrict__ x,
                                                        const float* __restrict__ Wh,
                                                        float* __restrict__ partials) {
    const int g     = blockIdx.x % NGROUPS;
    const int split = blockIdx.x / NGROUPS;
    const int t     = threadIdx.x;

    const float4* x4  = (const float4*)x;
    const float4* Wh4 = (const float4*)Wh;

    float acc[RGROUP][HEADS];
#pragma unroll
    for (int r = 0; r < RGROUP; ++r)
#pragma unroll
        for (int h = 0; h < HEADS; ++h) acc[r][h] = 0.f;

    // this split covers float4 indices [split*2048, (split+1)*2048)
    const int base_k4 = split * (K4 / SPLITS) + t;

#pragma unroll
    for (int i = 0; i < (K4 / SPLITS) / 256; ++i) {   // 8 iterations
        const int k4 = base_k4 + i * 256;
        float4 wv[HEADS];
#pragma unroll
        for (int h = 0; h < HEADS; ++h) wv[h] = Wh4[h * K4 + k4];
#pragma unroll
        for (int r = 0; r < RGROUP; ++r) {
            float4 xv = x4[(size_t)(g * RGROUP + r) * K4 + k4];
#pragma unroll
            for (int h = 0; h < HEADS; ++h) {
                acc[r][h] += xv.x * wv[h].x + xv.y * wv[h].y
                           + xv.z * wv[h].z + xv.w * wv[h].w;
            }
        }
    }

    // wave (64-lane) reduction of the 32 accumulators
    const int lane = t & 63;
    const int wave = t >> 6;   // 0..3
    __shared__ float red[4][RGROUP * HEADS];
#pragma unroll
    for (int r = 0; r < RGROUP; ++r) {
#pragma unroll
        for (int h = 0; h < HEADS; ++h) {
            float v = acc[r][h];
#pragma unroll
            for (int off = 32; off > 0; off >>= 1) v += __shfl_down(v, off);
            if (lane == 0) red[wave][r * HEADS + h] = v;
        }
    }
    __syncthreads();
    if (t < RGROUP * HEADS) {
        float v = red[0][t] + red[1][t] + red[2][t] + red[3][t];
        const int r = t >> 3;   // /8
        const int h = t & 7;
        const int bn = g * RGROUP + r;
        partials[(size_t)split * (ROWS * HEADS) + bn * HEADS + h] = v;
    }
}

// ---------------------------------------------------------------------------
// Kernel 3: out[bn][h*10+m] = relu( (sum_s partials[s][bn][h]) * adj[bn][m] )
// ---------------------------------------------------------------------------
__global__ __launch_bounds__(256) void finalize_kernel(const float* __restrict__ partials,
                                                       const float* __restrict__ adj,
                                                       float* __restrict__ out,
                                                       int out_size) {
    int idx = blockIdx.x * blockDim.x + threadIdx.x;
    if (idx >= out_size) return;
    int bn  = idx / (HEADS * NN);
    int rem = idx % (HEADS * NN);
    int h = rem / NN;
    int m = rem % NN;
    float s = 0.f;
#pragma unroll
    for (int sp = 0; sp < SPLITS; ++sp)
        s += partials[(size_t)sp * (ROWS * HEADS) + bn * HEADS + h];
    float v = s * adj[bn * NN + m];
    out[idx] = v > 0.f ? v : 0.f;
}

extern "C" void kernel_launch(void* const* d_in, const int* in_sizes, int n_in,
                              void* d_out, int out_size, void* d_ws, size_t ws_size,
                              hipStream_t stream) {
    const float* x   = (const float*)d_in[0];   // (32,10,65536)
    const float* adj = (const float*)d_in[1];   // (32,10,10)
    const float* W   = (const float*)d_in[2];   // (64,65536)
    float* out = (float*)d_out;                 // (32,10,80) = 25600 floats

    // workspace layout: Wh (8*65536 floats = 2 MiB) | partials (8*320*8 floats)
    float* Wh       = (float*)d_ws;
    float* partials = Wh + (size_t)HEADS * IN_DIM;

    // K1: reduce W -> Wh. 8*16384 = 131072 threads.
    wreduce_kernel<<<(HEADS * K4) / 256, 256, 0, stream>>>(W, Wh);

    // K2: partial GEMV. 80 groups x 8 splits = 640 blocks.
    gemv_part_kernel<<<NGROUPS * SPLITS, 256, 0, stream>>>(x, Wh, partials);

    // K3: finalize. 25600 outputs.
    finalize_kernel<<<(out_size + 255) / 256, 256, 0, stream>>>(partials, adj, out, out_size);
}

// Round 2
// 32.155 us; speedup vs baseline: 1.7910x; 1.7910x over previous
//
#include <hip/hip_runtime.h>
#include <hip/hip_bf16.h>

// Problem constants
#define BB 32
#define NN 10
#define IN_DIM 65536
#define OUT_DIM 64
#define HEADS 8
#define DD 8              // OUT_DIM / HEADS
#define ROWS (BB*NN)      // 320 "bn" rows
#define K4 (IN_DIM/4)     // 16384 float4 per row
#define SPLITS 32
#define KSPLIT (K4/SPLITS)      // 512 float4 per split
#define RGROUP 4
#define NGROUPS (ROWS/RGROUP)   // 80

// ---------------------------------------------------------------------------
// Kernel 1: Wh[h][k] = sum_{d=0..7} W[h*8+d][k]   (W is 64 x 65536 row-major)
// ---------------------------------------------------------------------------
__global__ __launch_bounds__(256) void wreduce_kernel(const float* __restrict__ W,
                                                      float* __restrict__ Wh) {
    int idx = blockIdx.x * blockDim.x + threadIdx.x;   // 0 .. 8*16384-1
    int h  = idx >> 14;        // / 16384
    int k4 = idx & 16383;      // % 16384
    const float4* W4 = (const float4*)W;
    float4 s = make_float4(0.f, 0.f, 0.f, 0.f);
#pragma unroll
    for (int d = 0; d < DD; ++d) {
        float4 v = W4[(h * DD + d) * K4 + k4];
        s.x += v.x; s.y += v.y; s.z += v.z; s.w += v.w;
    }
    ((float4*)Wh)[h * K4 + k4] = s;
}

// ---------------------------------------------------------------------------
// Kernel 2: partial GEMV. s[bn][h] = x[bn][:] . Wh[h][:]
// grid = NGROUPS * SPLITS = 2560 blocks, 256 threads.
// Block -> (row group g of 4 rows, k-split of 512 float4s).
// Wave w (of 4) owns heads {2w, 2w+1}; its 64 lanes sweep the k-split.
// All 4 waves read the same x float4s (L1-served after first wave).
// Writes partials[split][bn][h]  (SPLITS x 320 x 8 floats)
// ---------------------------------------------------------------------------
__global__ __launch_bounds__(256) void gemv_part_kernel(const float* __restrict__ x,
                                                        const float* __restrict__ Wh,
                                                        float* __restrict__ partials) {
    const int g     = blockIdx.x % NGROUPS;
    const int split = blockIdx.x / NGROUPS;
    const int t     = threadIdx.x;
    const int lane  = t & 63;
    const int wave  = t >> 6;      // 0..3
    const int h0    = wave * 2;    // this wave's first head

    const float4* x4  = (const float4*)x;
    const float4* Wh4 = (const float4*)Wh;

    float acc[RGROUP][2];
#pragma unroll
    for (int r = 0; r < RGROUP; ++r) { acc[r][0] = 0.f; acc[r][1] = 0.f; }

    const int kbase = split * KSPLIT + lane;

#pragma unroll 4
    for (int i = 0; i < KSPLIT / 64; ++i) {   // 8 iterations
        const int k4 = kbase + i * 64;
        float4 w0 = Wh4[(size_t)(h0 + 0) * K4 + k4];
        float4 w1 = Wh4[(size_t)(h0 + 1) * K4 + k4];
#pragma unroll
        for (int r = 0; r < RGROUP; ++r) {
            float4 xv = x4[(size_t)(g * RGROUP + r) * K4 + k4];
            acc[r][0] += xv.x * w0.x + xv.y * w0.y + xv.z * w0.z + xv.w * w0.w;
            acc[r][1] += xv.x * w1.x + xv.y * w1.y + xv.z * w1.z + xv.w * w1.w;
        }
    }

    // reduce each of the 8 accumulators across the 64 lanes
#pragma unroll
    for (int r = 0; r < RGROUP; ++r) {
#pragma unroll
        for (int h = 0; h < 2; ++h) {
            float v = acc[r][h];
#pragma unroll
            for (int off = 32; off > 0; off >>= 1) v += __shfl_down(v, off);
            acc[r][h] = v;
        }
    }

    if (lane == 0) {
        float* p = partials + (size_t)split * (ROWS * HEADS);
#pragma unroll
        for (int r = 0; r < RGROUP; ++r) {
            const int bn = g * RGROUP + r;
            p[bn * HEADS + h0 + 0] = acc[r][0];
            p[bn * HEADS + h0 + 1] = acc[r][1];
        }
    }
}

// ---------------------------------------------------------------------------
// Kernel 3: out[bn][h*10+m] = relu( (sum_s partials[s][bn][h]) * adj[bn][m] )
// ---------------------------------------------------------------------------
__global__ __launch_bounds__(256) void finalize_kernel(const float* __restrict__ partials,
                                                       const float* __restrict__ adj,
                                                       float* __restrict__ out,
                                                       int out_size) {
    int idx = blockIdx.x * blockDim.x + threadIdx.x;
    if (idx >= out_size) return;
    int bn  = idx / (HEADS * NN);
    int rem = idx % (HEADS * NN);
    int h = rem / NN;
    int m = rem % NN;
    float s = 0.f;
#pragma unroll
    for (int sp = 0; sp < SPLITS; ++sp)
        s += partials[(size_t)sp * (ROWS * HEADS) + bn * HEADS + h];
    float v = s * adj[bn * NN + m];
    out[idx] = v > 0.f ? v : 0.f;
}

extern "C" void kernel_launch(void* const* d_in, const int* in_sizes, int n_in,
                              void* d_out, int out_size, void* d_ws, size_t ws_size,
                              hipStream_t stream) {
    const float* x   = (const float*)d_in[0];   // (32,10,65536)
    const float* adj = (const float*)d_in[1];   // (32,10,10)
    const float* W   = (const float*)d_in[2];   // (64,65536)
    float* out = (float*)d_out;                 // (32,10,80) = 25600 floats

    // workspace layout: Wh (8*65536 floats = 2 MiB) | partials (32*320*8 floats)
    float* Wh       = (float*)d_ws;
    float* partials = Wh + (size_t)HEADS * IN_DIM;

    // K1: reduce W -> Wh. 8*16384 = 131072 threads.
    wreduce_kernel<<<(HEADS * K4) / 256, 256, 0, stream>>>(W, Wh);

    // K2: partial GEMV. 80 groups x 32 splits = 2560 blocks.
    gemv_part_kernel<<<NGROUPS * SPLITS, 256, 0, stream>>>(x, Wh, partials);

    // K3: finalize. 25600 outputs.
    finalize_kernel<<<(out_size + 255) / 256, 256, 0, stream>>>(partials, adj, out, out_size);
}